// Round 8
// baseline (181.729 us; speedup 1.0000x reference)
//
#include <hip/hip_runtime.h>

#define NTYPES 11
#define BLOCK  256
#define ITEMS  8
#define CHUNK  (BLOCK * ITEMS)   // 2048 atoms per block

// ---------------------------------------------------------------------------
// Kernel 1: per-block per-type histogram.
// bc[t*B + b] = number of atoms of type t in block b's chunk.
// ---------------------------------------------------------------------------
__global__ __launch_bounds__(BLOCK) void hist_kernel(
    const int* __restrict__ types, int N, int B, int* __restrict__ bc) {
  __shared__ int shCnt[NTYPES];
  const int tid = threadIdx.x;
  const int b = blockIdx.x;
  if (tid < NTYPES) shCnt[tid] = 0;
  __syncthreads();

  const int run = b * CHUNK + tid * ITEMS;
  int cnt[NTYPES];
#pragma unroll
  for (int t = 0; t < NTYPES; ++t) cnt[t] = 0;

  if (run < N) {
    const int4* p = (const int4*)(types + run);
    int4 a0 = p[0], a1 = p[1];
    int ty[ITEMS] = {a0.x, a0.y, a0.z, a0.w, a1.x, a1.y, a1.z, a1.w};
#pragma unroll
    for (int k = 0; k < ITEMS; ++k) {
#pragma unroll
      for (int t = 0; t < NTYPES; ++t) cnt[t] += (ty[k] == t) ? 1 : 0;
    }
  }

  const int lane = tid & 63;
#pragma unroll
  for (int t = 0; t < NTYPES; ++t) {
    int v = cnt[t];
    for (int o = 32; o >= 1; o >>= 1) v += __shfl_down(v, o);
    if (lane == 0) atomicAdd(&shCnt[t], v);
  }
  __syncthreads();
  if (tid < NTYPES) bc[tid * B + b] = shCnt[tid];
}

// ---------------------------------------------------------------------------
// Kernel 2: stable scatter with LDS bucket staging + INLINE prefix-sum.
// Each block recomputes (from the tiny L2-resident bc array):
//   shTot[t] = total count of type t  (all blocks)
//   shPre[t] = count of type t in blocks < b
// Wave w handles types {w, w+4, w+8}. Then proceeds exactly like R4:
// stable in-block rank -> type-sorted LDS staging -> coalesced contiguous
// copy-out per type segment. Block 0 also writes counts/offsets tail.
// ---------------------------------------------------------------------------
__global__ __launch_bounds__(BLOCK) void scatter_kernel(
    const float* __restrict__ coords, const int* __restrict__ types,
    const int* __restrict__ bc, int N, int B, float* __restrict__ out,
    float* __restrict__ outTail) {
  __shared__ float shC[CHUNK * 3];      // 24 KB type-sorted coords
  __shared__ int wtot[NTYPES][4];       // per-wave inclusive totals
  __shared__ int shOff[NTYPES + 1];     // local bucket offsets (exclusive)
  __shared__ int shDelta[NTYPES];       // 3*(globalBase[t] - shOff[t])
  __shared__ int shTot[NTYPES];         // global per-type totals
  __shared__ int shPre[NTYPES];         // per-type totals of blocks < b

  const int tid = threadIdx.x;
  const int b = blockIdx.x;
  const int lane = tid & 63;
  const int wave = tid >> 6;
  const int run = b * CHUNK + tid * ITEMS;
  const bool active = (run < N);

  // ---- Inline scan phase: wave w reduces types w, w+4, w+8 over bc ----
  for (int t = wave; t < NTYPES; t += 4) {
    const int* bt = bc + t * B;
    int tot = 0, pre = 0;
    for (int base = 0; base < B; base += 64) {
      const int idx = base + lane;
      const int v = (idx < B) ? bt[idx] : 0;
      tot += v;
      pre += (idx < b) ? v : 0;
    }
#pragma unroll
    for (int m = 32; m >= 1; m >>= 1) {
      tot += __shfl_xor(tot, m);
      pre += __shfl_xor(pre, m);
    }
    if (lane == 0) {
      shTot[t] = tot;
      shPre[t] = pre;
    }
  }

  // ---- Load types + histogram (as R4) ----
  int ty[ITEMS];
  int cnt[NTYPES];
#pragma unroll
  for (int t = 0; t < NTYPES; ++t) cnt[t] = 0;
#pragma unroll
  for (int k = 0; k < ITEMS; ++k) ty[k] = -1;

  if (active) {
    const int4* p = (const int4*)(types + run);
    int4 a0 = p[0], a1 = p[1];
    int tt[ITEMS] = {a0.x, a0.y, a0.z, a0.w, a1.x, a1.y, a1.z, a1.w};
#pragma unroll
    for (int k = 0; k < ITEMS; ++k) ty[k] = tt[k];
#pragma unroll
    for (int k = 0; k < ITEMS; ++k) {
#pragma unroll
      for (int t = 0; t < NTYPES; ++t) cnt[t] += (ty[k] == t) ? 1 : 0;
    }
  }

  // Wave-level stable exclusive scan per type.
  int rank[NTYPES];
#pragma unroll
  for (int t = 0; t < NTYPES; ++t) {
    int incl = cnt[t];
#pragma unroll
    for (int o = 1; o < 64; o <<= 1) {
      int v = __shfl_up(incl, o);
      if (lane >= o) incl += v;
    }
    if (lane == 63) wtot[t][wave] = incl;
    rank[t] = incl - cnt[t];  // exclusive within wave
  }
  __syncthreads();

  // Local bucket offsets + global deltas (threads 0..NTYPES-1).
  if (tid < NTYPES) {
    int loc = 0;
    for (int u = 0; u < tid; ++u)
      loc += wtot[u][0] + wtot[u][1] + wtot[u][2] + wtot[u][3];
    shOff[tid] = loc;
    int off = 0;
    for (int u = 0; u < tid; ++u) off += shTot[u];
    const int gb = off + shPre[tid];  // global atom base for (type, block)
    shDelta[tid] = 3 * (gb - loc);
    if (tid == NTYPES - 1) {
      shOff[NTYPES] =
          loc + wtot[tid][0] + wtot[tid][1] + wtot[tid][2] + wtot[tid][3];
    }
    if (b == 0) {
      outTail[tid] = (float)shTot[tid];    // counts (as float values)
      outTail[NTYPES + tid] = (float)off;  // offsets (as float values)
    }
  }
  __syncthreads();

  // Finalize local ranks: bucket base + wave base + lane-exclusive.
#pragma unroll
  for (int t = 0; t < NTYPES; ++t) {
    int wb = 0;
#pragma unroll
    for (int w = 0; w < 3; ++w) wb += (w < wave) ? wtot[t][w] : 0;
    rank[t] += wb + shOff[t];
  }

  // Scatter coords into type-sorted LDS buffer.
  if (active) {
    float c[ITEMS * 3];
    const float4* cp = (const float4*)(coords + (size_t)run * 3);
#pragma unroll
    for (int q = 0; q < (ITEMS * 3) / 4; ++q) {
      float4 v = cp[q];
      c[4 * q + 0] = v.x;
      c[4 * q + 1] = v.y;
      c[4 * q + 2] = v.z;
      c[4 * q + 3] = v.w;
    }
#pragma unroll
    for (int k = 0; k < ITEMS; ++k) {
      const int t0 = ty[k];
      int slot = 0;
#pragma unroll
      for (int t = 0; t < NTYPES; ++t) {
        if (t0 == t) {
          slot = rank[t];
          rank[t] += 1;
        }
      }
      shC[3 * slot + 0] = c[3 * k + 0];
      shC[3 * slot + 1] = c[3 * k + 1];
      shC[3 * slot + 2] = c[3 * k + 2];
    }
  }
  __syncthreads();

  // Coalesced copy-out: slot s -> global float index 3*s + delta3[type(s)].
  const int total = shOff[NTYPES];
  int offr[NTYPES];
  int dlt[NTYPES];
#pragma unroll
  for (int t = 0; t < NTYPES; ++t) {
    offr[t] = shOff[t];
    dlt[t] = shDelta[t];
  }
#pragma unroll
  for (int k = 0; k < ITEMS; ++k) {
    const int s = k * BLOCK + tid;
    if (s < total) {
      int d = dlt[0];
#pragma unroll
      for (int t = 1; t < NTYPES; ++t) d = (s >= offr[t]) ? dlt[t] : d;
      const int src = 3 * s;
      out[src + d + 0] = shC[src + 0];
      out[src + d + 1] = shC[src + 1];
      out[src + d + 2] = shC[src + 2];
    }
  }
}

extern "C" void kernel_launch(void* const* d_in, const int* in_sizes, int n_in,
                              void* d_out, int out_size, void* d_ws,
                              size_t ws_size, hipStream_t stream) {
  const float* coords = (const float*)d_in[0];
  const int* types = (const int*)d_in[1];
  const int N = in_sizes[1];              // 4,000,000 atoms
  const int B = (N + CHUNK - 1) / CHUNK;  // 1954 blocks

  int* bc = (int*)d_ws;  // [NTYPES * B]
  float* out = (float*)d_out;
  float* outTail = out + (size_t)3 * N;  // counts then offsets, as floats

  hist_kernel<<<B, BLOCK, 0, stream>>>(types, N, B, bc);
  scatter_kernel<<<B, BLOCK, 0, stream>>>(coords, types, bc, N, B, out,
                                          outTail);
}